// Round 3
// baseline (84.831 us; speedup 1.0000x reference)
//
#include <hip/hip_runtime.h>
#include <math.h>

// Problem constants (reference: x [8,2,224,224] f32, weights [1,4] f32)
#define BATCH 8
#define CIN   2
#define H     224
#define W     224
#define NH    223
#define NW    223
#define PIXB  (H * W)          // floats per channel per batch = 50176
#define NPB   (CIN * H * W)    // floats per batch = 100352
#define N4    (NPB / 4)        // 25088 float4 per batch
#define PER_B (NH * NW)        // output positions per batch = 49729
#define TPR   56               // thread-slots per output row (4 positions each)
#define SLOTS (NH * TPR)       // 12488 slots per batch
#define QBLK  ((SLOTS + 255) / 256)   // 49 blocks per batch
#define PI_F  3.14159265358979323846f

// Single fused kernel, grid (QBLK, BATCH) x 256. No workspace, no second
// launch: each block redundantly reduces its batch's full image (401 KB,
// L2-resident) to min/max, then computes its slice of the analytic circuit.
//   z_q = cos(a_q) cos(b_q) cos(w_q) - sin(a_q) sin(w_q)
//   out[b,0]=z1 z2 z3; out[b,1]=z0 z1; out[b,2]=z0 z1 z2; out[b,3]=z0 z1 z2 z3
__global__ __launch_bounds__(256) void fused_quanv(
        const float* __restrict__ x, const float* __restrict__ wts,
        float* __restrict__ out) {
    const int b = blockIdx.y;

    // ---- Phase 1: per-block redundant min/max over batch b (98 f4/thread) ----
    const float4* xb = (const float4*)(x + (size_t)b * NPB);
    float lmin =  INFINITY, lmax = -INFINITY;
    for (int idx = threadIdx.x; idx < N4; idx += 256) {
        float4 v = xb[idx];
        lmin = fminf(lmin, fminf(fminf(v.x, v.y), fminf(v.z, v.w)));
        lmax = fmaxf(lmax, fmaxf(fmaxf(v.x, v.y), fmaxf(v.z, v.w)));
    }
    #pragma unroll
    for (int off = 32; off > 0; off >>= 1) {
        lmin = fminf(lmin, __shfl_down(lmin, off, 64));
        lmax = fmaxf(lmax, __shfl_down(lmax, off, 64));
    }
    __shared__ float smin[4], smax[4], sred[2];
    const int wid = threadIdx.x >> 6;
    if ((threadIdx.x & 63) == 0) { smin[wid] = lmin; smax[wid] = lmax; }
    __syncthreads();
    if (threadIdx.x == 0) {
        #pragma unroll
        for (int i = 1; i < 4; ++i) {
            lmin = fminf(lmin, smin[i]);
            lmax = fmaxf(lmax, smax[i]);
        }
        sred[0] = lmin;
        sred[1] = lmax;
    }
    __syncthreads();
    const float gmin  = sred[0];
    const float scale = PI_F / (sred[1] - gmin + 1e-8f);

    // Weight trig: uniform values, 4 sincos per thread (cheap, trans pipe idle)
    float sw[4], cw[4];
    #pragma unroll
    for (int q = 0; q < 4; ++q) __sincosf(wts[q], &sw[q], &cw[q]);

    // ---- Phase 2: 4 consecutive output positions per thread ----
    const int slot = blockIdx.x * 256 + threadIdx.x;
    if (slot >= SLOTS) return;
    const int i  = slot / TPR;
    const int jt = (slot - i * TPR) * 4;          // 0,4,...,220
    const int npos = (jt == 220) ? 3 : 4;         // last slot covers 3 positions

    // Aligned float4 loads: W=224 (mult of 4), jt mult of 4, PIXB mult of 4.
    const float* r0 = x + (size_t)b * NPB + i * W + jt;   // ch0 row i
    const float* r1 = r0 + W;                             // ch0 row i+1
    const float* r2 = r0 + PIXB;                          // ch1 row i
    const float* r3 = r2 + W;                             // ch1 row i+1
    float4 v0 = *(const float4*)r0;
    float4 v1 = *(const float4*)r1;
    float4 v2 = *(const float4*)r2;
    float4 v3 = *(const float4*)r3;
    float e0 = 0.f, e1 = 0.f, e2 = 0.f, e3 = 0.f;
    if (jt < 220) { e0 = r0[4]; e1 = r1[4]; e2 = r2[4]; e3 = r3[4]; }

    const float p0[5] = {v0.x, v0.y, v0.z, v0.w, e0};   // ch0 row i   -> RX a
    const float p1[5] = {v1.x, v1.y, v1.z, v1.w, e1};   // ch0 row i+1 -> RX a
    const float p2[5] = {v2.x, v2.y, v2.z, v2.w, e2};   // ch1 row i   -> RY b
    const float p3[5] = {v3.x, v3.y, v3.z, v3.w, e3};   // ch1 row i+1 -> RY b

    float sa0[5], ca0[5], sa1[5], ca1[5], cb0[5], cb1[5];
    #pragma unroll
    for (int k = 0; k < 5; ++k) {
        __sincosf((p0[k] - gmin) * scale, &sa0[k], &ca0[k]);
        __sincosf((p1[k] - gmin) * scale, &sa1[k], &ca1[k]);
        cb0[k] = __cosf((p2[k] - gmin) * scale);
        cb1[k] = __cosf((p3[k] - gmin) * scale);
    }

    const size_t obase = (size_t)b * 4 * PER_B + (size_t)i * NW + jt;
    #pragma unroll
    for (int p = 0; p < 4; ++p) {
        if (p < npos) {
            // q0=(0,0) q1=(0,1) q2=(1,0) q3=(1,1); a from ch0, b from ch1
            float z0 = ca0[p]     * cb0[p]     * cw[0] - sa0[p]     * sw[0];
            float z1 = ca0[p + 1] * cb0[p + 1] * cw[1] - sa0[p + 1] * sw[1];
            float z2 = ca1[p]     * cb1[p]     * cw[2] - sa1[p]     * sw[2];
            float z3 = ca1[p + 1] * cb1[p + 1] * cw[3] - sa1[p + 1] * sw[3];
            float z01 = z0 * z1;
            out[obase + p]             = z1 * z2 * z3;
            out[obase + PER_B + p]     = z01;
            out[obase + 2 * PER_B + p] = z01 * z2;
            out[obase + 3 * PER_B + p] = z01 * z2 * z3;
        }
    }
}

extern "C" void kernel_launch(void* const* d_in, const int* in_sizes, int n_in,
                              void* d_out, int out_size, void* d_ws, size_t ws_size,
                              hipStream_t stream) {
    const float* x   = (const float*)d_in[0];   // [8,2,224,224] f32
    const float* wts = (const float*)d_in[1];   // [1,4] f32
    float* out = (float*)d_out;                 // [8,4,223,223] f32

    fused_quanv<<<dim3(QBLK, BATCH), 256, 0, stream>>>(x, wts, out);
}